// Round 1
// baseline (266.254 us; speedup 1.0000x reference)
//
#include <hip/hip_runtime.h>
#include <stdint.h>

typedef unsigned long long u64;
typedef unsigned int u32;
typedef float f32x2 __attribute__((ext_vector_type(2)));

constexpr int kC  = 256;
constexpr int kHW = 3136;             // 56*56
constexpr int kN  = 32;
constexpr int kP  = kN * kHW;         // 100352 spatial positions
constexpr int kPos = 128;             // positions per block (even -> float2 never straddles n)
constexpr int kBlk = kP / kPos;       // 784  (~3 blocks/CU, 12 waves/CU)

// d_ws layout (bytes):
constexpr size_t OFF_T     = 0;      // u64 [4][256]  packed w-sign planes (plane-major)
constexpr size_t OFF_SCALE = 8192;   // f32 [256]
constexpr size_t OFF_SUMD  = 9216;   // i64 [256]  sum of dot
constexpr size_t OFF_SUMD2 = 11264;  // i64 [256]  sum of dot^2
constexpr size_t OFF_S     = 13312;  // u64 [4][kP] packed x-sign planes (SoA), 32B-aligned

struct alignas(16) U64x2 { u64 x, y; };

// ---------------------------------------------------------------------------
// Kernel A: w-prep. 16 blocks x 256. Builds T (w-sign planes) + scale;
// block 0 zeros the stat accumulators. ~2 us, reads 256 KB.
// ---------------------------------------------------------------------------
__global__ __launch_bounds__(256) void prep_kernel(
    const float* __restrict__ w, char* __restrict__ ws) {
  int t = threadIdx.x;
  int b = blockIdx.x;
  u64*   T     = (u64*)(ws + OFF_T);
  float* scale = (float*)(ws + OFF_SCALE);
  int kk = t >> 6, ln = t & 63;
  if (b == 0) {
    ((u64*)(ws + OFF_SUMD))[t]  = 0ull;
    ((u64*)(ws + OFF_SUMD2))[t] = 0ull;
  }
  __shared__ float part[4][16];
#pragma unroll
  for (int i = 0; i < 16; ++i) {
    int o = b * 16 + i;
    float v = w[o * kC + kk * 64 + ln];   // coalesced 256B/wave
    u64 m = __ballot(v >= 0.0f);
    float a = fabsf(v);
#pragma unroll
    for (int s = 32; s > 0; s >>= 1) a += __shfl_xor(a, s, 64);
    if (ln == 0) { T[kk * 256 + o] = m; part[kk][i] = a; }
  }
  __syncthreads();
  if (t < 16) {
    int o = b * 16 + t;
    scale[o] = (part[0][t] + part[1][t] + part[2][t] + part[3][t]) * (1.0f / 256.0f);
  }
}

// ---------------------------------------------------------------------------
// Kernel B: fused sign-pack + batch stats.
// Pack phase: wave k packs channels [64k,64k+64) for 128 positions, 2 pos/lane
//   via float2 loads (8 B/lane, coalescing sweet spot). Plain (cached) loads:
//   x seeds L3 for the finalize re-read. S stored as 16 B/lane U64x2.
// Stats phase (after barrier): thread t = channel o popcounts the block's own
//   128 positions straight back out of L1/L2-hot S (uniform broadcast loads),
//   hidden under other blocks' HBM fetch. 2 atomics/thread.
// ---------------------------------------------------------------------------
__global__ __launch_bounds__(256) void pack_stats_kernel(
    const float* __restrict__ x, const float* __restrict__ bias0,
    char* __restrict__ ws) {
  int t = threadIdx.x;
  int k    = __builtin_amdgcn_readfirstlane(t >> 6);  // wave-uniform chunk
  int lane = t & 63;
  u32 pb = blockIdx.x * (u32)kPos;
  u32 p  = pb + 2u * (u32)lane;        // even -> float2 stays inside one (n,c) row
  u32 n  = p / kHW;
  u32 hw = p - n * kHW;
  const float* xp = x + (size_t)n * kC * kHW + (size_t)(k * 64) * kHW + hw;
  const float* bp = bias0 + k * 64;    // uniform -> s_load

  u64 m0 = 0, m1 = 0;
#pragma unroll 8
  for (int i = 0; i < 64; ++i) {
    f32x2 v = *(const f32x2*)(xp + (size_t)i * kHW);   // 512 B/wave per channel
    float bi = bp[i];
    m0 |= (u64)(v.x + bi >= 0.0f) << i;
    m1 |= (u64)(v.y + bi >= 0.0f) << i;
  }
  u64* S = (u64*)(ws + OFF_S);
  U64x2 st; st.x = m0; st.y = m1;
  *(U64x2*)&S[(size_t)k * kP + p] = st;               // 16 B/lane, 1 KB/wave

  __syncthreads();   // drains vmcnt -> block's S visible to all 4 waves

  const u64* T = (const u64*)(ws + OFF_T);
  u64 t0 = T[t], t1 = T[256 + t], t2 = T[512 + t], t3 = T[768 + t];
  int summ = 0, summ2 = 0;
#pragma unroll 8
  for (int j = 0; j < kPos; j += 2) {
    u32 q = pb + j;                                   // uniform -> broadcast
    U64x2 a0 = *(const U64x2*)&S[q];
    U64x2 a1 = *(const U64x2*)&S[kP + q];
    U64x2 a2 = *(const U64x2*)&S[2 * kP + q];
    U64x2 a3 = *(const U64x2*)&S[3 * kP + q];
    int ka = __popcll(a0.x ^ t0) + __popcll(a1.x ^ t1) +
             __popcll(a2.x ^ t2) + __popcll(a3.x ^ t3);
    int kb = __popcll(a0.y ^ t0) + __popcll(a1.y ^ t1) +
             __popcll(a2.y ^ t2) + __popcll(a3.y ^ t3);
    int ma = 128 - ka, mb = 128 - kb;
    summ  += ma + mb;
    summ2 += ma * ma + mb * mb;
  }
  atomicAdd((u64*)(ws + OFF_SUMD) + t,  (u64)(long long)(2 * summ));
  atomicAdd((u64*)(ws + OFF_SUMD2) + t, (u64)(long long)(4 * summ2));
}

// ---------------------------------------------------------------------------
// Kernel C: BN coefs + fused epilogue, 2 positions/lane.
//   u = 2*cA*(128-kx) + cB + x ;  out = (u>0 ? u : alpha*u) + bias2
// x loads plain (expected L3-resident from kernel B); out stores NT
// (pure stream -- keep x resident in L3 while we drain).
// ---------------------------------------------------------------------------
__global__ __launch_bounds__(256) void finalize_kernel(
    const float* __restrict__ x, const float* __restrict__ gamma,
    const float* __restrict__ beta, const float* __restrict__ bias1,
    const float* __restrict__ alpha, const float* __restrict__ bias2,
    const char* __restrict__ ws, float* __restrict__ out) {
  __shared__ u64    ldsT[256][4];   // [o][plane]: broadcast ds_read_b128 x2
  __shared__ float4 ldsC[256];      // {2*cA, cB, alpha, bias2}

  int t = threadIdx.x;
  {
    const u64* T = (const u64*)(ws + OFF_T);
#pragma unroll
    for (int q = 0; q < 4; ++q) ldsT[t][q] = T[q * 256 + t];

    const float*     scale = (const float*)(ws + OFF_SCALE);
    const long long* sumd  = (const long long*)(ws + OFF_SUMD);
    const long long* sumd2 = (const long long*)(ws + OFF_SUMD2);
    double inv  = 1.0 / (double)kP;
    double md   = (double)sumd[t] * inv;
    double e2   = (double)sumd2[t] * inv;
    double vard = e2 - md * md;
    float sc  = scale[t];
    float mu  = sc * (float)md;
    float var = sc * sc * (float)vard;
    float rs  = rsqrtf(var + 1e-5f);
    float g   = gamma[t];
    float cA  = g * rs * sc;
    float cB  = beta[t] - g * rs * mu + bias1[t];
    ldsC[t] = make_float4(2.0f * cA, cB, alpha[t], bias2[t]);
  }
  __syncthreads();

  int k    = __builtin_amdgcn_readfirstlane(t >> 6);
  int lane = t & 63;
  u32 p  = blockIdx.x * (u32)kPos + 2u * (u32)lane;
  u32 n  = p / kHW;
  u32 hw = p - n * kHW;

  const u64* S = (const u64*)(ws + OFF_S);
  U64x2 s0 = *(const U64x2*)&S[p];                    // 16 B/lane, L2-hot
  U64x2 s1 = *(const U64x2*)&S[kP + p];
  U64x2 s2 = *(const U64x2*)&S[2 * kP + p];
  U64x2 s3 = *(const U64x2*)&S[3 * kP + p];

  const float* xp = x   + (size_t)n * kC * kHW + (size_t)(k * 64) * kHW + hw;
  float*       op = out + (size_t)n * kC * kHW + (size_t)(k * 64) * kHW + hw;

#pragma unroll 8
  for (int i = 0; i < 64; ++i) {
    int o = k * 64 + i;                // wave-uniform -> LDS broadcast
    u64 w0 = ldsT[o][0], w1 = ldsT[o][1], w2 = ldsT[o][2], w3 = ldsT[o][3];
    float4 cc = ldsC[o];
    f32x2 xv = *(const f32x2*)(xp + (size_t)i * kHW);  // 512 B/wave, L3-hit
    int ka = __popcll(s0.x ^ w0) + __popcll(s1.x ^ w1) +
             __popcll(s2.x ^ w2) + __popcll(s3.x ^ w3);
    int kb = __popcll(s0.y ^ w0) + __popcll(s1.y ^ w1) +
             __popcll(s2.y ^ w2) + __popcll(s3.y ^ w3);
    float ua = fmaf(cc.x, (float)(128 - ka), cc.y) + xv.x;
    float ub = fmaf(cc.x, (float)(128 - kb), cc.y) + xv.y;
    f32x2 r;
    r.x = (ua > 0.0f ? ua : cc.z * ua) + cc.w;
    r.y = (ub > 0.0f ? ub : cc.z * ub) + cc.w;
    __builtin_nontemporal_store(r, (f32x2*)(op + (size_t)i * kHW));
  }
}

extern "C" void kernel_launch(void* const* d_in, const int* in_sizes, int n_in,
                              void* d_out, int out_size, void* d_ws, size_t ws_size,
                              hipStream_t stream) {
  const float* x     = (const float*)d_in[0];
  const float* bias0 = (const float*)d_in[1];
  const float* w     = (const float*)d_in[2];
  const float* gamma = (const float*)d_in[3];
  const float* beta  = (const float*)d_in[4];
  const float* bias1 = (const float*)d_in[5];
  const float* alpha = (const float*)d_in[6];
  const float* bias2 = (const float*)d_in[7];
  float* out = (float*)d_out;
  char*  ws  = (char*)d_ws;

  hipLaunchKernelGGL(prep_kernel, dim3(16), dim3(256), 0, stream, w, ws);
  hipLaunchKernelGGL(pack_stats_kernel, dim3(kBlk), dim3(256), 0, stream,
                     x, bias0, ws);
  hipLaunchKernelGGL(finalize_kernel, dim3(kBlk), dim3(256), 0, stream,
                     x, gamma, beta, bias1, alpha, bias2, ws, out);
}

// Round 2
// 246.266 us; speedup vs baseline: 1.0812x; 1.0812x over previous
//
#include <hip/hip_runtime.h>
#include <stdint.h>

typedef unsigned long long u64;
typedef unsigned int u32;

constexpr int kC  = 256;
constexpr int kHW = 3136;             // 56*56
constexpr int kN  = 32;
constexpr int kP  = kN * kHW;         // 100352 spatial positions
constexpr int kPosPk = 64;            // positions per pack/finalize block
constexpr int kBlkPk = kP / kPosPk;   // 1568  (~24 waves/CU ceiling)
constexpr int kPosSt = 128;           // positions per stats block
constexpr int kBlkSt = kP / kPosSt;   // 784
constexpr int kRedBlk = 16;           // reduce blocks (784 = 16*49 rows)
constexpr int kRedRows = 49;

// d_ws layout (bytes):
constexpr size_t OFF_T     = 0;        // u64 [4][256]  packed w-sign planes (plane-major)
constexpr size_t OFF_SCALE = 8192;     // f32 [256]
constexpr size_t OFF_SUMD  = 9216;     // i64 [256]  sum of dot
constexpr size_t OFF_SUMD2 = 11264;    // i64 [256]  sum of dot^2
constexpr size_t OFF_S     = 13312;    // u64 [4][kP] packed x-sign planes (SoA)
constexpr size_t OFF_PS    = 3224576;  // i32 [784][256] per-block summ partials
constexpr size_t OFF_PQ    = 4027392;  // i32 [784][256] per-block summ2 partials

struct alignas(16) U64x2 { u64 x, y; };

// ---------------------------------------------------------------------------
// Kernel A: w-prep. 16 blocks x 256. Builds T (w-sign planes) + scale;
// block 0 zeros the stat accumulators. ~2 us, reads 256 KB.
// ---------------------------------------------------------------------------
__global__ __launch_bounds__(256) void prep_kernel(
    const float* __restrict__ w, char* __restrict__ ws) {
  int t = threadIdx.x;
  int b = blockIdx.x;
  u64*   T     = (u64*)(ws + OFF_T);
  float* scale = (float*)(ws + OFF_SCALE);
  int kk = t >> 6, ln = t & 63;
  if (b == 0) {
    ((u64*)(ws + OFF_SUMD))[t]  = 0ull;
    ((u64*)(ws + OFF_SUMD2))[t] = 0ull;
  }
  __shared__ float part[4][16];
#pragma unroll
  for (int i = 0; i < 16; ++i) {
    int o = b * 16 + i;
    float v = w[o * kC + kk * 64 + ln];   // coalesced 256B/wave
    u64 m = __ballot(v >= 0.0f);
    float a = fabsf(v);
#pragma unroll
    for (int s = 32; s > 0; s >>= 1) a += __shfl_xor(a, s, 64);
    if (ln == 0) { T[kk * 256 + o] = m; part[kk][i] = a; }
  }
  __syncthreads();
  if (t < 16) {
    int o = b * 16 + t;
    scale[o] = (part[0][t] + part[1][t] + part[2][t] + part[3][t]) * (1.0f / 256.0f);
  }
}

// ---------------------------------------------------------------------------
// Kernel B: sign-pack x. Round-0 proven structure: 1 position/lane, grid 1568
// (~24 waves/CU), NT scalar loads (pure stream), 8B/lane S store.
// ---------------------------------------------------------------------------
__global__ __launch_bounds__(256) void pack_kernel(
    const float* __restrict__ x, const float* __restrict__ bias0,
    char* __restrict__ ws) {
  int t = threadIdx.x;
  int b = blockIdx.x;
  int k    = __builtin_amdgcn_readfirstlane(t >> 6);  // wave-uniform chunk
  int lane = t & 63;
  u32 p  = (u32)b * (u32)kPosPk + (u32)lane;
  u32 n  = p / kHW;
  u32 hw = p - n * kHW;
  const float* xp = x + (size_t)n * kC * kHW + (size_t)(k * 64) * kHW + hw;
  const float* bp = bias0 + k * 64;                   // uniform -> s_load

  u64 m = 0;
#pragma unroll 32
  for (int i = 0; i < 64; ++i) {
    float v = __builtin_nontemporal_load(xp + (size_t)i * kHW) + bp[i];
    m |= (u64)(v >= 0.0f) << i;
  }
  u64* S = (u64*)(ws + OFF_S);
  S[(size_t)k * kP + p] = m;                          // 8B/lane, 512B/wave
}

// ---------------------------------------------------------------------------
// Kernel C: stats partials. thread = output channel o; uniform broadcast
// loads of S (L2-hot), pure VALU xor/popc. NO ATOMICS: each block writes its
// 2x256 i32 partials coalesced (2 KB contiguous, zero contention).
// ---------------------------------------------------------------------------
__global__ __launch_bounds__(256) void stats_kernel(char* __restrict__ ws) {
  int o = threadIdx.x;
  const u64* T = (const u64*)(ws + OFF_T);
  u64 t0 = T[o], t1 = T[256 + o], t2 = T[512 + o], t3 = T[768 + o];
  const u64* S = (const u64*)(ws + OFF_S);
  u32 pb = blockIdx.x * (u32)kPosSt;

  int summ = 0, summ2 = 0;
#pragma unroll 8
  for (int j = 0; j < kPosSt; j += 2) {
    u32 p = pb + j;                                  // uniform -> broadcast
    U64x2 a0 = *(const U64x2*)&S[p];
    U64x2 a1 = *(const U64x2*)&S[kP + p];
    U64x2 a2 = *(const U64x2*)&S[2 * kP + p];
    U64x2 a3 = *(const U64x2*)&S[3 * kP + p];
    int ka = __popcll(a0.x ^ t0) + __popcll(a1.x ^ t1) +
             __popcll(a2.x ^ t2) + __popcll(a3.x ^ t3);
    int kb = __popcll(a0.y ^ t0) + __popcll(a1.y ^ t1) +
             __popcll(a2.y ^ t2) + __popcll(a3.y ^ t3);
    int ma = 128 - ka, mb = 128 - kb;
    summ  += ma + mb;
    summ2 += ma * ma + mb * mb;
  }
  ((int*)(ws + OFF_PS))[blockIdx.x * 256 + o] = summ;   // coalesced 1 KB
  ((int*)(ws + OFF_PQ))[blockIdx.x * 256 + o] = summ2;  // coalesced 1 KB
}

// ---------------------------------------------------------------------------
// Kernel D: reduce partials. 16 blocks x 256; thread sums 49 rows of its
// channel column (256 B/wave coalesced, L2-resident), then ONE u64 atomic
// per stat (16 atomics/address total -- negligible contention).
// ---------------------------------------------------------------------------
__global__ __launch_bounds__(256) void reduce_kernel(char* __restrict__ ws) {
  int t = threadIdx.x;
  int b = blockIdx.x;
  const int* PS = (const int*)(ws + OFF_PS);
  const int* PQ = (const int*)(ws + OFF_PQ);
  long long s = 0, q = 0;
#pragma unroll 7
  for (int r = 0; r < kRedRows; ++r) {
    int row = b * kRedRows + r;
    s += PS[row * 256 + t];
    q += PQ[row * 256 + t];
  }
  atomicAdd((u64*)(ws + OFF_SUMD) + t,  (u64)(long long)(2 * s));
  atomicAdd((u64*)(ws + OFF_SUMD2) + t, (u64)(long long)(4 * q));
}

// ---------------------------------------------------------------------------
// Kernel E: BN coefs + fused epilogue (round-0 proven structure).
//   u = 2*cA*m + cB + x ;  out = (u>0 ? u : alpha*u) + bias2
// x loads / out stores non-temporal (pure streams); S loads normal (L2-hot).
// ---------------------------------------------------------------------------
__global__ __launch_bounds__(256) void finalize_kernel(
    const float* __restrict__ x, const float* __restrict__ gamma,
    const float* __restrict__ beta, const float* __restrict__ bias1,
    const float* __restrict__ alpha, const float* __restrict__ bias2,
    const char* __restrict__ ws, float* __restrict__ out) {
  __shared__ u64    ldsT[256][4];   // [o][plane]: broadcast ds_read_b128 x2
  __shared__ float4 ldsC[256];      // {2*cA, cB, alpha, bias2}

  int t = threadIdx.x;
  {
    const u64* T = (const u64*)(ws + OFF_T);
#pragma unroll
    for (int q = 0; q < 4; ++q) ldsT[t][q] = T[q * 256 + t];

    const float*     scale = (const float*)(ws + OFF_SCALE);
    const long long* sumd  = (const long long*)(ws + OFF_SUMD);
    const long long* sumd2 = (const long long*)(ws + OFF_SUMD2);
    double inv  = 1.0 / (double)kP;
    double md   = (double)sumd[t] * inv;
    double e2   = (double)sumd2[t] * inv;
    double vard = e2 - md * md;
    float sc  = scale[t];
    float mu  = sc * (float)md;
    float var = sc * sc * (float)vard;
    float rs  = rsqrtf(var + 1e-5f);
    float g   = gamma[t];
    float cA  = g * rs * sc;
    float cB  = beta[t] - g * rs * mu + bias1[t];
    ldsC[t] = make_float4(2.0f * cA, cB, alpha[t], bias2[t]);
  }
  __syncthreads();

  int k    = __builtin_amdgcn_readfirstlane(t >> 6);
  int lane = t & 63;
  u32 p  = blockIdx.x * (u32)kPosPk + (u32)lane;
  u32 n  = p / kHW;
  u32 hw = p - n * kHW;

  const u64* S = (const u64*)(ws + OFF_S);
  u64 s0 = S[p];                       // 8B/lane coalesced, L2-hot
  u64 s1 = S[kP + p];
  u64 s2 = S[2 * kP + p];
  u64 s3 = S[3 * kP + p];

  const float* xp = x   + (size_t)n * kC * kHW + (size_t)(k * 64) * kHW + hw;
  float*       op = out + (size_t)n * kC * kHW + (size_t)(k * 64) * kHW + hw;

#pragma unroll 8
  for (int i = 0; i < 64; ++i) {
    int o = k * 64 + i;                // wave-uniform -> LDS broadcast
    u64 w0 = ldsT[o][0], w1 = ldsT[o][1], w2 = ldsT[o][2], w3 = ldsT[o][3];
    int kx = __popcll(s0 ^ w0) + __popcll(s1 ^ w1) +
             __popcll(s2 ^ w2) + __popcll(s3 ^ w3);
    float4 cc = ldsC[o];
    float xv = __builtin_nontemporal_load(xp + (size_t)i * kHW);
    float u  = fmaf(cc.x, (float)(128 - kx), cc.y) + xv;
    float r  = u > 0.0f ? u : cc.z * u;
    __builtin_nontemporal_store(r + cc.w, op + (size_t)i * kHW);
  }
}

extern "C" void kernel_launch(void* const* d_in, const int* in_sizes, int n_in,
                              void* d_out, int out_size, void* d_ws, size_t ws_size,
                              hipStream_t stream) {
  const float* x     = (const float*)d_in[0];
  const float* bias0 = (const float*)d_in[1];
  const float* w     = (const float*)d_in[2];
  const float* gamma = (const float*)d_in[3];
  const float* beta  = (const float*)d_in[4];
  const float* bias1 = (const float*)d_in[5];
  const float* alpha = (const float*)d_in[6];
  const float* bias2 = (const float*)d_in[7];
  float* out = (float*)d_out;
  char*  ws  = (char*)d_ws;

  hipLaunchKernelGGL(prep_kernel, dim3(16), dim3(256), 0, stream, w, ws);
  hipLaunchKernelGGL(pack_kernel, dim3(kBlkPk), dim3(256), 0, stream,
                     x, bias0, ws);
  hipLaunchKernelGGL(stats_kernel, dim3(kBlkSt), dim3(256), 0, stream, ws);
  hipLaunchKernelGGL(reduce_kernel, dim3(kRedBlk), dim3(256), 0, stream, ws);
  hipLaunchKernelGGL(finalize_kernel, dim3(kBlkPk), dim3(256), 0, stream,
                     x, gamma, beta, bias1, alpha, bias2, ws, out);
}